// Round 9
// baseline (206.994 us; speedup 1.0000x reference)
//
#include <hip/hip_runtime.h>
#include <hip/hip_bf16.h>
#include <math.h>

#define SRATE   44100
#define HOPSZ   512
#define NFFT    2048
#define PADW    1024
#define NBINS   540
#define NFRAMES 431
#define NSAMP   220500
#define NBATCH  16

#define PI_D 3.14159265358979323846

typedef __attribute__((ext_vector_type(8))) short short8;
typedef __attribute__((ext_vector_type(4))) float f32x4;

// ======================= PATH A: split-K balanced GEMM ======================
// M = batch*frames = 6896 rows. Tile 128x128, BK=32, 4 waves 2x2 (64x64/wave).
// r8-PROVEN 3-buffer depth-2 counted-vmcnt pipeline, unchanged.
// NEW: heavy N-tiles (nt 0..5) split into 2 K-chunks -> 15 jobs x 54 = 810
// blocks (3.16/CU, LPT order). Split chunks rendezvous via device-scope
// atomics: each writes complex partial to its own sub-slot; second arriver
// combines in registers and runs the magnitude epilogue.
#define MROWS   (NBATCH * NFRAMES)      // 6896
#define BM2     128
#define BN2     128
#define BK2     32
#define MT2     54                      // ceil(6896/128)
#define NT2     9
#define NJOBS   15                      // 6 split nt (2 chunks) + 3 mono
#define SPLITNT 6                       // nt < 6 are split
#define FLAGN   (SPLITNT * MT2)         // 324 rendezvous cells
#define TABCOLS 1152                    // 9*128 cols (bins >=540 zero)
#define XPITCH  222552                  // bf16 elems per batch (NSAMP+2048 -> mult 8)
#define XPTOT   (NBATCH * XPITCH)       // 3,560,832 elems
#define NCHUNK  (XPITCH / 8)            // 27819
#define CVTBLK  ((NBATCH * NCHUNK + 255) / 256)   // 1739
// ws byte offsets
#define JOBS_OFF  ((size_t)(XPTOT + (size_t)TABCOLS * NFFT) * 2)  // 11,840,256
#define FLAGS_OFF (JOBS_OFF + 256)
#define PART_OFF  ((size_t)16 * 1024 * 1024)
#define NEED_A    (PART_OFF + (size_t)FLAGN * 2 * 16384 * 8)      // ~59.2 MB

// ---- fused prep: x->bf16 xp + LINEAR atom table + job list + flag zero -----
__global__ void prep_all(const float* __restrict__ x,
                         __hip_bfloat16* __restrict__ xp,
                         __hip_bfloat16* __restrict__ tab,
                         int4* __restrict__ jobs,
                         int* __restrict__ flags) {
    const int bid = blockIdx.x;
    if (bid < CVTBLK) {
        const int idx = bid * 256 + threadIdx.x;
        if (idx >= NBATCH * NCHUNK) return;
        const int b  = idx / NCHUNK;
        const int c  = idx - b * NCHUNK;
        const int i0 = c * 8;
        const float* xb = x + (size_t)b * NSAMP;
        const int g0 = i0 - PADW;
        union { short8 v; unsigned short u[8]; } pk;
        if (g0 >= 0 && g0 + 8 <= NSAMP) {
            const float4 f0 = *(const float4*)(xb + g0);
            const float4 f1 = *(const float4*)(xb + g0 + 4);
            const float vv[8] = {f0.x, f0.y, f0.z, f0.w, f1.x, f1.y, f1.z, f1.w};
            #pragma unroll
            for (int e = 0; e < 8; ++e) {
                __hip_bfloat16 h = __float2bfloat16(vv[e]);
                pk.u[e] = *(unsigned short*)&h;
            }
        } else {
            #pragma unroll
            for (int e = 0; e < 8; ++e) {
                const int g = g0 + e;
                const float v = (g >= 0 && g < NSAMP) ? xb[g] : 0.f;
                __hip_bfloat16 h = __float2bfloat16(v);
                pk.u[e] = *(unsigned short*)&h;
            }
        }
        *(short8*)(xp + (size_t)b * XPITCH + i0) = pk.v;
        return;
    }
    if (bid == CVTBLK + TABCOLS) {
        // ---- build job list (LPT desc) + zero rendezvous flags -------------
        __shared__ int s_k0[NT2], s_ns[NT2];
        const int nt = threadIdx.x;
        if (nt < NT2) {
            const int    bin0  = (nt * BN2) >> 1;
            const double freq  = 27.5 * exp2((double)bin0 / 60.0);
            const double r     = exp2(2.0 / 60.0);
            const double alpha = (r - 1.0) / (r + 1.0);
            const double len   = (1.0 / alpha) * (double)SRATE / (freq + 30.0 / alpha);
            const int    nk    = (int)floor(len);
            const int    s     = (NFFT - nk) / 2;
            const int    k0    = s & ~(BK2 - 1);
            int          k1    = (s + nk + BK2 - 1) & ~(BK2 - 1);
            if (k1 > NFFT) k1 = NFFT;
            s_k0[nt] = k0;
            s_ns[nt] = (k1 - k0) / BK2;
        }
        __syncthreads();
        if (threadIdx.x == 0) {
            int4 tmp[NJOBS];
            int jo = 0;
            for (int q = 0; q < NT2; ++q) {
                if (q < SPLITNT) {
                    const int s  = s_ns[q];
                    const int h0 = (s + 1) >> 1, h1 = s - h0;
                    tmp[jo++] = make_int4(q, s_k0[q], h0, 0);
                    tmp[jo++] = make_int4(q, s_k0[q] + h0 * BK2, h1, 1);
                } else {
                    tmp[jo++] = make_int4(q, s_k0[q], s_ns[q], -1);
                }
            }
            for (int a = 0; a < NJOBS; ++a) {          // selection sort desc steps
                int best = a;
                for (int b2 = a + 1; b2 < NJOBS; ++b2)
                    if (tmp[b2].z > tmp[best].z) best = b2;
                const int4 t4 = tmp[a]; tmp[a] = tmp[best]; tmp[best] = t4;
            }
            for (int a = 0; a < NJOBS; ++a) jobs[a] = tmp[a];
        }
        for (int i = threadIdx.x; i < FLAGN; i += 256) flags[i] = 0;
        return;
    }
    // ---- atom table col (LINEAR layout [col][k]) ---------------------------
    const int col = bid - CVTBLK;                     // 0..1151
    const int bin = col >> 1;
    const int ri  = col & 1;
    __hip_bfloat16* row = tab + (size_t)col * NFFT;
    {
        const short8 z8 = {0,0,0,0,0,0,0,0};
        *(short8*)(row + threadIdx.x * 8) = z8;       // zero all 2048
    }
    if (bin >= NBINS) return;
    __syncthreads();
    const double freq  = 27.5 * exp2((double)bin / 60.0);
    const double r     = exp2(2.0 / 60.0);
    const double alpha = (r - 1.0) / (r + 1.0);
    const double len   = (1.0 / alpha) * (double)SRATE / (freq + 30.0 / alpha);
    const int    nk    = (int)floor(len);
    const int    s     = (NFFT - nk) / 2;
    const float  ampf  = (float)((2.0 / (double)(nk - 1)) / sqrt(len));
    const float  winc  = 2.0f / (float)(nk - 1);
    const float  phsf  = (float)(2.0 * freq / (double)SRATE);  // revolutions/tap
    for (int tp = threadIdx.x; tp < nk; tp += 256) {
        const float w = 0.5f - 0.5f * cospif(winc * (float)tp);
        const float ph = fmodf(phsf * (float)tp, 2.0f);
        float sp, cp;
        sincospif(ph, &sp, &cp);
        const float val = ri ? (-w * ampf * sp) : (w * ampf * cp);
        row[s + tp] = __float2bfloat16(val);
    }
}

// ---- GEMM: out[row*540+bin] = |sum_k xp_row[k] * atom_col[k]| --------------
__global__ __launch_bounds__(256, 3) void vqt_gemm8(const __hip_bfloat16* __restrict__ xp,
                                                    const __hip_bfloat16* __restrict__ tab,
                                                    const int4* __restrict__ jobs,
                                                    int* __restrict__ flags,
                                                    float* __restrict__ partials,
                                                    float* __restrict__ out) {
    // 48 KB: 3 x [A 8K | B 8K]
    __shared__ uint4 smem4[3072];
    __shared__ int s_old;
    const int mt = blockIdx.x;
    const int4 J = jobs[blockIdx.y];
    const int nt = J.x, k0 = J.y, nsteps = J.z, sub = J.w;
    const int row0 = mt * BM2;
    const int n0   = nt * BN2;

    const int t    = threadIdx.x;
    const int lane = t & 63;
    const int w    = t >> 6;
    const int wr   = w >> 1, wc = w & 1;              // wave -> 64x64 quadrant
    const int l15  = lane & 15, kq = lane >> 4;

    // staging sources: thread t stages 16B chunk c = t + 256p (2 A + 2 B)
    const __hip_bfloat16* srcA[2];
    const __hip_bfloat16* srcB[2];
    #pragma unroll
    for (int p = 0; p < 2; ++p) {
        const int c   = t + 256 * p;                  // 0..511
        const int lr  = c >> 2;                       // row 0..127
        const int chp = c & 3;                        // phys chunk
        const int kqs = (chp - (lr >> 1)) & 3;        // k-chunk held by slot
        int row = row0 + lr;
        if (row > MROWS - 1) row = MROWS - 1;
        const int bb = row / NFRAMES;
        const int ff = row - bb * NFRAMES;
        srcA[p] = xp + (size_t)bb * XPITCH + (size_t)ff * HOPSZ + (kqs << 3) + k0;
        srcB[p] = tab + (size_t)(n0 + lr) * NFFT + (kqs << 3) + k0;
    }

    f32x4 acc[4][4] = {};

    // one STAGE = 4 gload_lds per thread (2 A + 2 B), advances K by 32
    #define STAGE(BUF)                                                            \
        do {                                                                      \
            const int cb = (BUF) * 1024;                                          \
            _Pragma("unroll")                                                     \
            for (int p = 0; p < 2; ++p) {                                         \
                __builtin_amdgcn_global_load_lds((const void*)srcA[p],            \
                    (void*)&smem4[cb + p * 256 + w * 64], 16, 0, 0);              \
                srcA[p] += BK2;                                                   \
            }                                                                     \
            _Pragma("unroll")                                                     \
            for (int p = 0; p < 2; ++p) {                                         \
                __builtin_amdgcn_global_load_lds((const void*)srcB[p],            \
                    (void*)&smem4[cb + 512 + p * 256 + w * 64], 16, 0, 0);        \
                srcB[p] += BK2;                                                   \
            }                                                                     \
        } while (0)

    STAGE(0);
    STAGE(1);

    // per-lane phys chunk for reads (r8-proven conflict-free layout)
    const int chrd = ((l15 >> 1) + kq) & 3;
    const int abase = (wr * 64 + l15) * 64 + chrd * 16;   // + i*1024
    const int bbase = (wc * 64 + l15) * 64 + chrd * 16;   // + j*1024

    int cur = 0, stg = 2;
    for (int step = 0; step < nsteps; ++step) {
        // r5/r8-PROVEN ordering: own-vmcnt -> barrier -> STAGE -> compute.
        if (step + 1 < nsteps) {
            asm volatile("s_waitcnt vmcnt(4)" ::: "memory");
        } else {
            asm volatile("s_waitcnt vmcnt(0)" ::: "memory");
        }
        __builtin_amdgcn_sched_barrier(0);
        __builtin_amdgcn_s_barrier();
        __builtin_amdgcn_sched_barrier(0);
        if (step + 2 < nsteps) {
            STAGE(stg);                               // WAR-safe: readers of stg
            stg = (stg == 2) ? 0 : stg + 1;           // passed this barrier
        }
        const char* Ab = (const char*)smem4 + cur * 16384;
        const char* Bb = Ab + 8192;
        short8 af[4], bf[4];
        #pragma unroll
        for (int i = 0; i < 4; ++i) af[i] = *(const short8*)(Ab + abase + i * 1024);
        #pragma unroll
        for (int j = 0; j < 4; ++j) bf[j] = *(const short8*)(Bb + bbase + j * 1024);
        #pragma unroll
        for (int i = 0; i < 4; ++i)
            #pragma unroll
            for (int j = 0; j < 4; ++j)
                acc[i][j] = __builtin_amdgcn_mfma_f32_16x16x32_bf16(af[i], bf[j], acc[i][j], 0, 0, 0);
        cur = (cur == 2) ? 0 : cur + 1;
    }
    #undef STAGE

    if (sub >= 0) {
        // ---- split-cell rendezvous: write my partial, second arriver combines
        const int flagSlot = nt * MT2 + mt;           // 0..323
        float4* base0 = (float4*)partials + (size_t)flagSlot * 8192;
        float4* mine  = base0 + sub * 4096;
        #pragma unroll
        for (int i = 0; i < 4; ++i)
            #pragma unroll
            for (int j = 0; j < 4; ++j) {
                float4 wv;
                wv.x = acc[i][j][0]; wv.y = acc[i][j][1];
                wv.z = acc[i][j][2]; wv.w = acc[i][j][3];
                mine[(i * 4 + j) * 256 + t] = wv;     // coalesced
            }
        __threadfence();                              // release (device scope)
        __syncthreads();
        if (t == 0) s_old = atomicAdd(&flags[flagSlot], 1);
        __syncthreads();
        if (s_old == 0) return;                       // first arriver: done
        __threadfence();                              // acquire side
        const float4* peer = base0 + (1 - sub) * 4096;
        #pragma unroll
        for (int i = 0; i < 4; ++i)
            #pragma unroll
            for (int j = 0; j < 4; ++j) {
                const float4 p = peer[(i * 4 + j) * 256 + t];
                acc[i][j][0] += p.x; acc[i][j][1] += p.y;
                acc[i][j][2] += p.z; acc[i][j][3] += p.w;
            }
    }

    // ---- epilogue: |(re,im)| of adjacent-lane pairs (r3-proven verbatim)
    const int rowb = row0 + wr * 64;
    const int binb = (n0 + wc * 64) >> 1;
    const int srcl = (lane & 48) | ((l15 & 7) << 1);
    #pragma unroll
    for (int i = 0; i < 4; ++i) {
        #pragma unroll
        for (int jp = 0; jp < 2; ++jp) {
            #pragma unroll
            for (int reg = 0; reg < 4; ++reg) {
                const float v0 = acc[i][2 * jp][reg];
                const float v1 = acc[i][2 * jp + 1][reg];
                const float p0 = __shfl_xor(v0, 1);
                const float p1 = __shfl_xor(v1, 1);
                const float m0 = sqrtf(v0 * v0 + p0 * p0);
                const float m1 = sqrtf(v1 * v1 + p1 * p1);
                const float r0 = __shfl(m0, srcl);
                const float r1 = __shfl(m1, srcl);
                const float m  = (l15 < 8) ? r0 : r1;
                const int row = rowb + i * 16 + kq * 4 + reg;
                const int bin = binb + jp * 16 + l15;
                if (row < MROWS && bin < NBINS)
                    out[(size_t)row * NBINS + bin] = m;
            }
        }
    }
}

// ======================= PATH B fallback: round-2 kernel ====================
#define NPADB   544
#define NCOLS   1088
#define BM 64
#define BN 64
#define BK 64
#define MTILES 7
#define NTILES 17
#define APITCH 72

__global__ void build_tab(__hip_bfloat16* __restrict__ tab) {
    const int bin = blockIdx.x;
    __hip_bfloat16* rowre = tab + (size_t)(2 * bin) * NFFT;
    __hip_bfloat16* rowim = rowre + NFFT;
    if (bin >= NBINS) {
        const __hip_bfloat16 z = __float2bfloat16(0.f);
        for (int t = threadIdx.x; t < NFFT; t += blockDim.x) { rowre[t] = z; rowim[t] = z; }
        return;
    }
    const double freq  = 27.5 * exp2((double)bin / 60.0);
    const double r     = exp2(2.0 / 60.0);
    const double alpha = (r - 1.0) / (r + 1.0);
    const double len   = (1.0 / alpha) * (double)SRATE / (freq + 30.0 / alpha);
    const int    nk    = (int)floor(len);
    const int    s     = (NFFT - nk) / 2;
    const double amp   = (2.0 / (double)(nk - 1)) / sqrt(len);
    for (int t = threadIdx.x; t < NFFT; t += blockDim.x) {
        float re = 0.f, im = 0.f;
        const int tp = t - s;
        if (tp >= 0 && tp < nk) {
            const double w  = 0.5 - 0.5 * cos(2.0 * PI_D * (double)tp / (double)(nk - 1));
            const double ph = fmod(2.0 * freq * (double)tp / (double)SRATE, 2.0);
            double sp, cp;
            sincospi(ph, &sp, &cp);
            re = (float)(w * amp * cp);
            im = (float)(-w * amp * sp);
        }
        rowre[t] = __float2bfloat16(re);
        rowim[t] = __float2bfloat16(im);
    }
}

__global__ __launch_bounds__(256) void vqt_gemm(const float* __restrict__ x,
                                                const __hip_bfloat16* __restrict__ tab,
                                                float* __restrict__ out) {
    __shared__ __hip_bfloat16 As[BM * APITCH];
    __shared__ __hip_bfloat16 Bs[BN * APITCH];
    const int mt = blockIdx.x, nt = blockIdx.y, b = blockIdx.z;
    const int n0 = nt * BN;
    const int    bin0  = n0 >> 1;
    const double freq  = 27.5 * exp2((double)bin0 / 60.0);
    const double r     = exp2(2.0 / 60.0);
    const double alpha = (r - 1.0) / (r + 1.0);
    const double len   = (1.0 / alpha) * (double)SRATE / (freq + 30.0 / alpha);
    const int    nk    = (int)floor(len);
    const int    s     = (NFFT - nk) / 2;
    const int    k0    = s & ~(BK - 1);
    int          k1    = (s + nk + BK - 1) & ~(BK - 1);
    if (k1 > NFFT) k1 = NFFT;
    const int tid  = threadIdx.x;
    const int lane = tid & 63;
    const int wid  = tid >> 6;
    const int wr   = wid >> 1, wc = wid & 1;
    const int sr   = tid >> 2, sq = tid & 3;
    const float* xb     = x + (size_t)b * NSAMP;
    const int    f_base = mt * BM;
    const long arow_off = (long)(f_base + sr) * HOPSZ - PADW + sq * 16;
    const __hip_bfloat16* brow = tab + (size_t)(n0 + sr) * NFFT + sq * 16;
    f32x4 acc[2][2] = {};
    for (int kt = k0; kt < k1; kt += BK) {
        union { short8 v[2]; unsigned short u[16]; } pk;
        #pragma unroll
        for (int v = 0; v < 4; ++v) {
            const long g = arow_off + kt + v * 4;
            float4 t4 = {0.f, 0.f, 0.f, 0.f};
            if (g >= 0 && g + 4 <= (long)NSAMP) t4 = *(const float4*)(xb + g);
            __hip_bfloat16 h0 = __float2bfloat16(t4.x);
            __hip_bfloat16 h1 = __float2bfloat16(t4.y);
            __hip_bfloat16 h2 = __float2bfloat16(t4.z);
            __hip_bfloat16 h3 = __float2bfloat16(t4.w);
            pk.u[4 * v + 0] = *(unsigned short*)&h0;
            pk.u[4 * v + 1] = *(unsigned short*)&h1;
            pk.u[4 * v + 2] = *(unsigned short*)&h2;
            pk.u[4 * v + 3] = *(unsigned short*)&h3;
        }
        { short8* dst = (short8*)(As + sr * APITCH + sq * 16); dst[0] = pk.v[0]; dst[1] = pk.v[1]; }
        { const short8* src = (const short8*)(brow + kt);
          short8* dst = (short8*)(Bs + sr * APITCH + sq * 16); dst[0] = src[0]; dst[1] = src[1]; }
        __syncthreads();
        #pragma unroll
        for (int ks = 0; ks < 2; ++ks) {
            const int kc = ks * 32 + (lane >> 4) * 8;
            const short8 a0 = *(const short8*)(As + (wr * 32 +      (lane & 15)) * APITCH + kc);
            const short8 a1 = *(const short8*)(As + (wr * 32 + 16 + (lane & 15)) * APITCH + kc);
            const short8 b0 = *(const short8*)(Bs + (wc * 32 +      (lane & 15)) * APITCH + kc);
            const short8 b1 = *(const short8*)(Bs + (wc * 32 + 16 + (lane & 15)) * APITCH + kc);
            acc[0][0] = __builtin_amdgcn_mfma_f32_16x16x32_bf16(a0, b0, acc[0][0], 0, 0, 0);
            acc[0][1] = __builtin_amdgcn_mfma_f32_16x16x32_bf16(a0, b1, acc[0][1], 0, 0, 0);
            acc[1][0] = __builtin_amdgcn_mfma_f32_16x16x32_bf16(a1, b0, acc[1][0], 0, 0, 0);
            acc[1][1] = __builtin_amdgcn_mfma_f32_16x16x32_bf16(a1, b1, acc[1][1], 0, 0, 0);
        }
        __syncthreads();
    }
    const int colc = lane & 15, rg = lane >> 4;
    float* outb = out + (size_t)b * NFRAMES * NBINS;
    #pragma unroll
    for (int i = 0; i < 2; ++i)
        #pragma unroll
        for (int j = 0; j < 2; ++j)
            #pragma unroll
            for (int reg = 0; reg < 4; ++reg) {
                const float v = acc[i][j][reg];
                const float p = __shfl_xor(v, 1);
                if (!(lane & 1)) {
                    const int f   = f_base + wr * 32 + i * 16 + rg * 4 + reg;
                    const int col = n0 + wc * 32 + j * 16 + colc;
                    const int bin = col >> 1;
                    if (f < NFRAMES && bin < NBINS)
                        outb[(size_t)f * NBINS + bin] = sqrtf(v * v + p * p);
                }
            }
}

extern "C" void kernel_launch(void* const* d_in, const int* in_sizes, int n_in,
                              void* d_out, int out_size, void* d_ws, size_t ws_size,
                              hipStream_t stream) {
    const float* x = (const float*)d_in[0];
    float* out = (float*)d_out;
    const size_t needB = (size_t)NCOLS * NFFT * sizeof(__hip_bfloat16); // 4.46 MB
    if (ws_size >= NEED_A) {
        __hip_bfloat16* xp   = (__hip_bfloat16*)d_ws;
        __hip_bfloat16* tab  = xp + XPTOT;
        int4* jobs  = (int4*)((char*)d_ws + JOBS_OFF);
        int*  flags = (int*)((char*)d_ws + FLAGS_OFF);
        float* partials = (float*)((char*)d_ws + PART_OFF);
        prep_all<<<dim3(CVTBLK + TABCOLS + 1), dim3(256), 0, stream>>>(x, xp, tab, jobs, flags);
        vqt_gemm8<<<dim3(MT2, NJOBS), dim3(256), 0, stream>>>(xp, tab, jobs, flags, partials, out);
    } else if (ws_size >= needB) {
        build_tab<<<dim3(NPADB), dim3(256), 0, stream>>>((__hip_bfloat16*)d_ws);
        vqt_gemm<<<dim3(MTILES, NTILES, NBATCH), dim3(256), 0, stream>>>(
            x, (const __hip_bfloat16*)d_ws, out);
    }
}

// Round 10
// 74.728 us; speedup vs baseline: 2.7700x; 2.7700x over previous
//
#include <hip/hip_runtime.h>
#include <hip/hip_bf16.h>
#include <math.h>

#define SRATE   44100
#define HOPSZ   512
#define NFFT    2048
#define PADW    1024
#define NBINS   540
#define NFRAMES 431
#define NSAMP   220500
#define NBATCH  16

#define PI_D 3.14159265358979323846

typedef __attribute__((ext_vector_type(8))) short short8;
typedef __attribute__((ext_vector_type(4))) float f32x4;

// ======================= PATH A: split-K balanced GEMM ======================
// r8-PROVEN GEMM inner loop (128x128 tile, BK=32, 3-buffer depth-2 counted
// vmcnt). Heavy N-tiles (nt 0..5) split into 2 K-chunks -> 15 jobs x 54 mt =
// 810 blocks, LPT order. Split chunks write fp32 complex partials (no fence,
// no atomic); a separate combine kernel (kernel-boundary sync) sums them and
// does the magnitude epilogue. Lesson r9: device-scope fences on CDNA4 cost
// L2 writeback/invalidate per block -- use dispatch boundaries instead.
#define MROWS   (NBATCH * NFRAMES)      // 6896
#define BM2     128
#define BN2     128
#define BK2     32
#define MT2     54                      // ceil(6896/128)
#define NT2     9
#define NJOBS   15                      // 6 split nt (2 chunks) + 3 mono
#define SPLITNT 6                       // nt < 6 are split
#define CELLN   (SPLITNT * MT2)         // 324 split cells
#define TABCOLS 1152                    // 9*128 cols (bins >=540 zero)
#define XPITCH  222552                  // bf16 elems per batch (NSAMP+2048 -> mult 8)
#define XPTOT   (NBATCH * XPITCH)       // 3,560,832 elems
#define NCHUNK  (XPITCH / 8)            // 27819
#define CVTBLK  ((NBATCH * NCHUNK + 255) / 256)   // 1739
// ws byte offsets
#define JOBS_OFF  ((size_t)(XPTOT + (size_t)TABCOLS * NFFT) * 2)  // 11,840,256
#define PART_OFF  ((size_t)16 * 1024 * 1024)
#define NEED_A    (PART_OFF + (size_t)CELLN * 2 * 16384 * 8)      // ~58.5 MB

// ---- fused prep: x->bf16 xp + LINEAR atom table + job list -----------------
__global__ void prep_all(const float* __restrict__ x,
                         __hip_bfloat16* __restrict__ xp,
                         __hip_bfloat16* __restrict__ tab,
                         int4* __restrict__ jobs) {
    const int bid = blockIdx.x;
    if (bid < CVTBLK) {
        const int idx = bid * 256 + threadIdx.x;
        if (idx >= NBATCH * NCHUNK) return;
        const int b  = idx / NCHUNK;
        const int c  = idx - b * NCHUNK;
        const int i0 = c * 8;
        const float* xb = x + (size_t)b * NSAMP;
        const int g0 = i0 - PADW;
        union { short8 v; unsigned short u[8]; } pk;
        if (g0 >= 0 && g0 + 8 <= NSAMP) {
            const float4 f0 = *(const float4*)(xb + g0);
            const float4 f1 = *(const float4*)(xb + g0 + 4);
            const float vv[8] = {f0.x, f0.y, f0.z, f0.w, f1.x, f1.y, f1.z, f1.w};
            #pragma unroll
            for (int e = 0; e < 8; ++e) {
                __hip_bfloat16 h = __float2bfloat16(vv[e]);
                pk.u[e] = *(unsigned short*)&h;
            }
        } else {
            #pragma unroll
            for (int e = 0; e < 8; ++e) {
                const int g = g0 + e;
                const float v = (g >= 0 && g < NSAMP) ? xb[g] : 0.f;
                __hip_bfloat16 h = __float2bfloat16(v);
                pk.u[e] = *(unsigned short*)&h;
            }
        }
        *(short8*)(xp + (size_t)b * XPITCH + i0) = pk.v;
        return;
    }
    if (bid == CVTBLK + TABCOLS) {
        // ---- build job list (LPT desc) -------------------------------------
        __shared__ int s_k0[NT2], s_ns[NT2];
        const int nt = threadIdx.x;
        if (nt < NT2) {
            const int    bin0  = (nt * BN2) >> 1;
            const double freq  = 27.5 * exp2((double)bin0 / 60.0);
            const double r     = exp2(2.0 / 60.0);
            const double alpha = (r - 1.0) / (r + 1.0);
            const double len   = (1.0 / alpha) * (double)SRATE / (freq + 30.0 / alpha);
            const int    nk    = (int)floor(len);
            const int    s     = (NFFT - nk) / 2;
            const int    k0    = s & ~(BK2 - 1);
            int          k1    = (s + nk + BK2 - 1) & ~(BK2 - 1);
            if (k1 > NFFT) k1 = NFFT;
            s_k0[nt] = k0;
            s_ns[nt] = (k1 - k0) / BK2;
        }
        __syncthreads();
        if (threadIdx.x == 0) {
            int4 tmp[NJOBS];
            int jo = 0;
            for (int q = 0; q < NT2; ++q) {
                if (q < SPLITNT) {
                    const int s  = s_ns[q];
                    const int h0 = (s + 1) >> 1, h1 = s - h0;
                    tmp[jo++] = make_int4(q, s_k0[q], h0, 0);
                    tmp[jo++] = make_int4(q, s_k0[q] + h0 * BK2, h1, 1);
                } else {
                    tmp[jo++] = make_int4(q, s_k0[q], s_ns[q], -1);
                }
            }
            for (int a = 0; a < NJOBS; ++a) {          // selection sort desc steps
                int best = a;
                for (int b2 = a + 1; b2 < NJOBS; ++b2)
                    if (tmp[b2].z > tmp[best].z) best = b2;
                const int4 t4 = tmp[a]; tmp[a] = tmp[best]; tmp[best] = t4;
            }
            for (int a = 0; a < NJOBS; ++a) jobs[a] = tmp[a];
        }
        return;
    }
    // ---- atom table col (LINEAR layout [col][k]) ---------------------------
    const int col = bid - CVTBLK;                     // 0..1151
    const int bin = col >> 1;
    const int ri  = col & 1;
    __hip_bfloat16* row = tab + (size_t)col * NFFT;
    {
        const short8 z8 = {0,0,0,0,0,0,0,0};
        *(short8*)(row + threadIdx.x * 8) = z8;       // zero all 2048
    }
    if (bin >= NBINS) return;
    __syncthreads();
    const double freq  = 27.5 * exp2((double)bin / 60.0);
    const double r     = exp2(2.0 / 60.0);
    const double alpha = (r - 1.0) / (r + 1.0);
    const double len   = (1.0 / alpha) * (double)SRATE / (freq + 30.0 / alpha);
    const int    nk    = (int)floor(len);
    const int    s     = (NFFT - nk) / 2;
    const float  ampf  = (float)((2.0 / (double)(nk - 1)) / sqrt(len));
    const float  winc  = 2.0f / (float)(nk - 1);
    const float  phsf  = (float)(2.0 * freq / (double)SRATE);  // revolutions/tap
    for (int tp = threadIdx.x; tp < nk; tp += 256) {
        const float w = 0.5f - 0.5f * cospif(winc * (float)tp);
        const float ph = fmodf(phsf * (float)tp, 2.0f);
        float sp, cp;
        sincospif(ph, &sp, &cp);
        const float val = ri ? (-w * ampf * sp) : (w * ampf * cp);
        row[s + tp] = __float2bfloat16(val);
    }
}

// ---- GEMM: out[row*540+bin] = |sum_k xp_row[k] * atom_col[k]| --------------
__global__ __launch_bounds__(256, 3) void vqt_gemm9(const __hip_bfloat16* __restrict__ xp,
                                                    const __hip_bfloat16* __restrict__ tab,
                                                    const int4* __restrict__ jobs,
                                                    float4* __restrict__ partials,
                                                    float* __restrict__ out) {
    // 48 KB: 3 x [A 8K | B 8K]
    __shared__ uint4 smem4[3072];
    const int mt = blockIdx.x;
    const int4 J = jobs[blockIdx.y];
    const int nt = J.x, k0 = J.y, nsteps = J.z, sub = J.w;
    const int row0 = mt * BM2;
    const int n0   = nt * BN2;

    const int t    = threadIdx.x;
    const int lane = t & 63;
    const int w    = t >> 6;
    const int wr   = w >> 1, wc = w & 1;              // wave -> 64x64 quadrant
    const int l15  = lane & 15, kq = lane >> 4;

    // staging sources: thread t stages 16B chunk c = t + 256p (2 A + 2 B)
    const __hip_bfloat16* srcA[2];
    const __hip_bfloat16* srcB[2];
    #pragma unroll
    for (int p = 0; p < 2; ++p) {
        const int c   = t + 256 * p;                  // 0..511
        const int lr  = c >> 2;                       // row 0..127
        const int chp = c & 3;                        // phys chunk
        const int kqs = (chp - (lr >> 1)) & 3;        // k-chunk held by slot
        int row = row0 + lr;
        if (row > MROWS - 1) row = MROWS - 1;
        const int bb = row / NFRAMES;
        const int ff = row - bb * NFRAMES;
        srcA[p] = xp + (size_t)bb * XPITCH + (size_t)ff * HOPSZ + (kqs << 3) + k0;
        srcB[p] = tab + (size_t)(n0 + lr) * NFFT + (kqs << 3) + k0;
    }

    f32x4 acc[4][4] = {};

    // one STAGE = 4 gload_lds per thread (2 A + 2 B), advances K by 32
    #define STAGE(BUF)                                                            \
        do {                                                                      \
            const int cb = (BUF) * 1024;                                          \
            _Pragma("unroll")                                                     \
            for (int p = 0; p < 2; ++p) {                                         \
                __builtin_amdgcn_global_load_lds((const void*)srcA[p],            \
                    (void*)&smem4[cb + p * 256 + w * 64], 16, 0, 0);              \
                srcA[p] += BK2;                                                   \
            }                                                                     \
            _Pragma("unroll")                                                     \
            for (int p = 0; p < 2; ++p) {                                         \
                __builtin_amdgcn_global_load_lds((const void*)srcB[p],            \
                    (void*)&smem4[cb + 512 + p * 256 + w * 64], 16, 0, 0);        \
                srcB[p] += BK2;                                                   \
            }                                                                     \
        } while (0)

    STAGE(0);
    STAGE(1);

    // per-lane phys chunk for reads (r8-proven conflict-free layout)
    const int chrd = ((l15 >> 1) + kq) & 3;
    const int abase = (wr * 64 + l15) * 64 + chrd * 16;   // + i*1024
    const int bbase = (wc * 64 + l15) * 64 + chrd * 16;   // + j*1024

    int cur = 0, stg = 2;
    for (int step = 0; step < nsteps; ++step) {
        // r5/r8-PROVEN ordering: own-vmcnt -> barrier -> STAGE -> compute.
        if (step + 1 < nsteps) {
            asm volatile("s_waitcnt vmcnt(4)" ::: "memory");
        } else {
            asm volatile("s_waitcnt vmcnt(0)" ::: "memory");
        }
        __builtin_amdgcn_sched_barrier(0);
        __builtin_amdgcn_s_barrier();
        __builtin_amdgcn_sched_barrier(0);
        if (step + 2 < nsteps) {
            STAGE(stg);                               // WAR-safe: readers of stg
            stg = (stg == 2) ? 0 : stg + 1;           // passed this barrier
        }
        const char* Ab = (const char*)smem4 + cur * 16384;
        const char* Bb = Ab + 8192;
        short8 af[4], bf[4];
        #pragma unroll
        for (int i = 0; i < 4; ++i) af[i] = *(const short8*)(Ab + abase + i * 1024);
        #pragma unroll
        for (int j = 0; j < 4; ++j) bf[j] = *(const short8*)(Bb + bbase + j * 1024);
        #pragma unroll
        for (int i = 0; i < 4; ++i)
            #pragma unroll
            for (int j = 0; j < 4; ++j)
                acc[i][j] = __builtin_amdgcn_mfma_f32_16x16x32_bf16(af[i], bf[j], acc[i][j], 0, 0, 0);
        cur = (cur == 2) ? 0 : cur + 1;
    }
    #undef STAGE

    if (sub >= 0) {
        // split chunk: write fp32 complex partial (coalesced), exit.
        // Visibility to vqt_combine is via the dispatch boundary (no fences).
        const int cell = nt * MT2 + mt;               // 0..323
        float4* mine = partials + (size_t)cell * 8192 + (size_t)sub * 4096;
        #pragma unroll
        for (int i = 0; i < 4; ++i)
            #pragma unroll
            for (int j = 0; j < 4; ++j) {
                float4 wv;
                wv.x = acc[i][j][0]; wv.y = acc[i][j][1];
                wv.z = acc[i][j][2]; wv.w = acc[i][j][3];
                mine[(i * 4 + j) * 256 + t] = wv;
            }
        return;
    }

    // ---- epilogue: |(re,im)| of adjacent-lane pairs (r3-proven verbatim)
    const int rowb = row0 + wr * 64;
    const int binb = (n0 + wc * 64) >> 1;
    const int srcl = (lane & 48) | ((l15 & 7) << 1);
    #pragma unroll
    for (int i = 0; i < 4; ++i) {
        #pragma unroll
        for (int jp = 0; jp < 2; ++jp) {
            #pragma unroll
            for (int reg = 0; reg < 4; ++reg) {
                const float v0 = acc[i][2 * jp][reg];
                const float v1 = acc[i][2 * jp + 1][reg];
                const float p0 = __shfl_xor(v0, 1);
                const float p1 = __shfl_xor(v1, 1);
                const float m0 = sqrtf(v0 * v0 + p0 * p0);
                const float m1 = sqrtf(v1 * v1 + p1 * p1);
                const float r0 = __shfl(m0, srcl);
                const float r1 = __shfl(m1, srcl);
                const float m  = (l15 < 8) ? r0 : r1;
                const int row = rowb + i * 16 + kq * 4 + reg;
                const int bin = binb + jp * 16 + l15;
                if (row < MROWS && bin < NBINS)
                    out[(size_t)row * NBINS + bin] = m;
            }
        }
    }
}

// ---- combine: sum the two fp32 partials of each split cell, magnitude ------
__global__ __launch_bounds__(256) void vqt_combine(const float4* __restrict__ partials,
                                                   float* __restrict__ out) {
    const int cell = blockIdx.x;                      // 0..323
    const int nt = cell / MT2, mt = cell - nt * MT2;
    const int row0 = mt * BM2;
    const int n0   = nt * BN2;

    const int t    = threadIdx.x;
    const int lane = t & 63;
    const int w    = t >> 6;
    const int wr   = w >> 1, wc = w & 1;
    const int l15  = lane & 15, kq = lane >> 4;

    const float4* base = partials + (size_t)cell * 8192;
    f32x4 acc[4][4];
    #pragma unroll
    for (int i = 0; i < 4; ++i)
        #pragma unroll
        for (int j = 0; j < 4; ++j) {
            const float4 a = base[(i * 4 + j) * 256 + t];
            const float4 b = base[4096 + (i * 4 + j) * 256 + t];
            acc[i][j][0] = a.x + b.x; acc[i][j][1] = a.y + b.y;
            acc[i][j][2] = a.z + b.z; acc[i][j][3] = a.w + b.w;
        }

    // r3-proven epilogue verbatim
    const int rowb = row0 + wr * 64;
    const int binb = (n0 + wc * 64) >> 1;
    const int srcl = (lane & 48) | ((l15 & 7) << 1);
    #pragma unroll
    for (int i = 0; i < 4; ++i) {
        #pragma unroll
        for (int jp = 0; jp < 2; ++jp) {
            #pragma unroll
            for (int reg = 0; reg < 4; ++reg) {
                const float v0 = acc[i][2 * jp][reg];
                const float v1 = acc[i][2 * jp + 1][reg];
                const float p0 = __shfl_xor(v0, 1);
                const float p1 = __shfl_xor(v1, 1);
                const float m0 = sqrtf(v0 * v0 + p0 * p0);
                const float m1 = sqrtf(v1 * v1 + p1 * p1);
                const float r0 = __shfl(m0, srcl);
                const float r1 = __shfl(m1, srcl);
                const float m  = (l15 < 8) ? r0 : r1;
                const int row = rowb + i * 16 + kq * 4 + reg;
                const int bin = binb + jp * 16 + l15;
                if (row < MROWS && bin < NBINS)
                    out[(size_t)row * NBINS + bin] = m;
            }
        }
    }
}

// ======================= PATH B fallback: round-2 kernel ====================
#define NPADB   544
#define NCOLS   1088
#define BM 64
#define BN 64
#define BK 64
#define MTILES 7
#define NTILES 17
#define APITCH 72

__global__ void build_tab(__hip_bfloat16* __restrict__ tab) {
    const int bin = blockIdx.x;
    __hip_bfloat16* rowre = tab + (size_t)(2 * bin) * NFFT;
    __hip_bfloat16* rowim = rowre + NFFT;
    if (bin >= NBINS) {
        const __hip_bfloat16 z = __float2bfloat16(0.f);
        for (int t = threadIdx.x; t < NFFT; t += blockDim.x) { rowre[t] = z; rowim[t] = z; }
        return;
    }
    const double freq  = 27.5 * exp2((double)bin / 60.0);
    const double r     = exp2(2.0 / 60.0);
    const double alpha = (r - 1.0) / (r + 1.0);
    const double len   = (1.0 / alpha) * (double)SRATE / (freq + 30.0 / alpha);
    const int    nk    = (int)floor(len);
    const int    s     = (NFFT - nk) / 2;
    const double amp   = (2.0 / (double)(nk - 1)) / sqrt(len);
    for (int t = threadIdx.x; t < NFFT; t += blockDim.x) {
        float re = 0.f, im = 0.f;
        const int tp = t - s;
        if (tp >= 0 && tp < nk) {
            const double w  = 0.5 - 0.5 * cos(2.0 * PI_D * (double)tp / (double)(nk - 1));
            const double ph = fmod(2.0 * freq * (double)tp / (double)SRATE, 2.0);
            double sp, cp;
            sincospi(ph, &sp, &cp);
            re = (float)(w * amp * cp);
            im = (float)(-w * amp * sp);
        }
        rowre[t] = __float2bfloat16(re);
        rowim[t] = __float2bfloat16(im);
    }
}

__global__ __launch_bounds__(256) void vqt_gemm(const float* __restrict__ x,
                                                const __hip_bfloat16* __restrict__ tab,
                                                float* __restrict__ out) {
    __shared__ __hip_bfloat16 As[BM * APITCH];
    __shared__ __hip_bfloat16 Bs[BN * APITCH];
    const int mt = blockIdx.x, nt = blockIdx.y, b = blockIdx.z;
    const int n0 = nt * BN;
    const int    bin0  = n0 >> 1;
    const double freq  = 27.5 * exp2((double)bin0 / 60.0);
    const double r     = exp2(2.0 / 60.0);
    const double alpha = (r - 1.0) / (r + 1.0);
    const double len   = (1.0 / alpha) * (double)SRATE / (freq + 30.0 / alpha);
    const int    nk    = (int)floor(len);
    const int    s     = (NFFT - nk) / 2;
    const int    k0    = s & ~(BK - 1);
    int          k1    = (s + nk + BK - 1) & ~(BK - 1);
    if (k1 > NFFT) k1 = NFFT;
    const int tid  = threadIdx.x;
    const int lane = tid & 63;
    const int wid  = tid >> 6;
    const int wr   = wid >> 1, wc = wid & 1;
    const int sr   = tid >> 2, sq = tid & 3;
    const float* xb     = x + (size_t)b * NSAMP;
    const int    f_base = mt * BM;
    const long arow_off = (long)(f_base + sr) * HOPSZ - PADW + sq * 16;
    const __hip_bfloat16* brow = tab + (size_t)(n0 + sr) * NFFT + sq * 16;
    f32x4 acc[2][2] = {};
    for (int kt = k0; kt < k1; kt += BK) {
        union { short8 v[2]; unsigned short u[16]; } pk;
        #pragma unroll
        for (int v = 0; v < 4; ++v) {
            const long g = arow_off + kt + v * 4;
            float4 t4 = {0.f, 0.f, 0.f, 0.f};
            if (g >= 0 && g + 4 <= (long)NSAMP) t4 = *(const float4*)(xb + g);
            __hip_bfloat16 h0 = __float2bfloat16(t4.x);
            __hip_bfloat16 h1 = __float2bfloat16(t4.y);
            __hip_bfloat16 h2 = __float2bfloat16(t4.z);
            __hip_bfloat16 h3 = __float2bfloat16(t4.w);
            pk.u[4 * v + 0] = *(unsigned short*)&h0;
            pk.u[4 * v + 1] = *(unsigned short*)&h1;
            pk.u[4 * v + 2] = *(unsigned short*)&h2;
            pk.u[4 * v + 3] = *(unsigned short*)&h3;
        }
        { short8* dst = (short8*)(As + sr * APITCH + sq * 16); dst[0] = pk.v[0]; dst[1] = pk.v[1]; }
        { const short8* src = (const short8*)(brow + kt);
          short8* dst = (short8*)(Bs + sr * APITCH + sq * 16); dst[0] = src[0]; dst[1] = src[1]; }
        __syncthreads();
        #pragma unroll
        for (int ks = 0; ks < 2; ++ks) {
            const int kc = ks * 32 + (lane >> 4) * 8;
            const short8 a0 = *(const short8*)(As + (wr * 32 +      (lane & 15)) * APITCH + kc);
            const short8 a1 = *(const short8*)(As + (wr * 32 + 16 + (lane & 15)) * APITCH + kc);
            const short8 b0 = *(const short8*)(Bs + (wc * 32 +      (lane & 15)) * APITCH + kc);
            const short8 b1 = *(const short8*)(Bs + (wc * 32 + 16 + (lane & 15)) * APITCH + kc);
            acc[0][0] = __builtin_amdgcn_mfma_f32_16x16x32_bf16(a0, b0, acc[0][0], 0, 0, 0);
            acc[0][1] = __builtin_amdgcn_mfma_f32_16x16x32_bf16(a0, b1, acc[0][1], 0, 0, 0);
            acc[1][0] = __builtin_amdgcn_mfma_f32_16x16x32_bf16(a1, b0, acc[1][0], 0, 0, 0);
            acc[1][1] = __builtin_amdgcn_mfma_f32_16x16x32_bf16(a1, b1, acc[1][1], 0, 0, 0);
        }
        __syncthreads();
    }
    const int colc = lane & 15, rg = lane >> 4;
    float* outb = out + (size_t)b * NFRAMES * NBINS;
    #pragma unroll
    for (int i = 0; i < 2; ++i)
        #pragma unroll
        for (int j = 0; j < 2; ++j)
            #pragma unroll
            for (int reg = 0; reg < 4; ++reg) {
                const float v = acc[i][j][reg];
                const float p = __shfl_xor(v, 1);
                if (!(lane & 1)) {
                    const int f   = f_base + wr * 32 + i * 16 + rg * 4 + reg;
                    const int col = n0 + wc * 32 + j * 16 + colc;
                    const int bin = col >> 1;
                    if (f < NFRAMES && bin < NBINS)
                        outb[(size_t)f * NBINS + bin] = sqrtf(v * v + p * p);
                }
            }
}

extern "C" void kernel_launch(void* const* d_in, const int* in_sizes, int n_in,
                              void* d_out, int out_size, void* d_ws, size_t ws_size,
                              hipStream_t stream) {
    const float* x = (const float*)d_in[0];
    float* out = (float*)d_out;
    const size_t needB = (size_t)NCOLS * NFFT * sizeof(__hip_bfloat16); // 4.46 MB
    if (ws_size >= NEED_A) {
        __hip_bfloat16* xp   = (__hip_bfloat16*)d_ws;
        __hip_bfloat16* tab  = xp + XPTOT;
        int4* jobs  = (int4*)((char*)d_ws + JOBS_OFF);
        float4* partials = (float4*)((char*)d_ws + PART_OFF);
        prep_all<<<dim3(CVTBLK + TABCOLS + 1), dim3(256), 0, stream>>>(x, xp, tab, jobs);
        vqt_gemm9<<<dim3(MT2, NJOBS), dim3(256), 0, stream>>>(xp, tab, jobs, partials, out);
        vqt_combine<<<dim3(CELLN), dim3(256), 0, stream>>>(partials, out);
    } else if (ws_size >= needB) {
        build_tab<<<dim3(NPADB), dim3(256), 0, stream>>>((__hip_bfloat16*)d_ws);
        vqt_gemm<<<dim3(MTILES, NTILES, NBATCH), dim3(256), 0, stream>>>(
            x, (const __hip_bfloat16*)d_ws, out);
    }
}

// Round 11
// 61.733 us; speedup vs baseline: 3.3531x; 1.2105x over previous
//
#include <hip/hip_runtime.h>
#include <hip/hip_bf16.h>
#include <math.h>

#define SRATE   44100
#define HOPSZ   512
#define NFFT    2048
#define PADW    1024
#define NBINS   540
#define NFRAMES 431
#define NSAMP   220500
#define NBATCH  16

#define PI_D 3.14159265358979323846

typedef __attribute__((ext_vector_type(8))) short short8;
typedef __attribute__((ext_vector_type(4))) float f32x4;

// =================== PATH A: persistent-chain pipelined GEMM ================
// M = batch*frames = 6896 rows, tile 128x128, BK=32, 4 waves 2x2 (64x64/wave).
// r8/r10-PROVEN per-step sync: vmcnt(4) -> barrier -> STAGE -> compute, 3x16KB
// buffers. NEW: each block runs a CHAIN of 1-2 N-tile segments (40-46 steps
// total) with the pipeline never draining across segment boundaries; direct
// per-segment epilogue. 54 mt x 7 chains = 378 long blocks (m102 small-K
// lesson: steps/block is the lever, not residency/balance).
#define MROWS   (NBATCH * NFRAMES)      // 6896
#define BM2     128
#define BN2     128
#define BK2     32
#define MT2     54                      // ceil(6896/128)
#define NT2     9
#define NCHAINS 7
#define TABCOLS 1152                    // 9*128 cols (bins >=540 zero)
#define XPITCH  222552                  // bf16 elems per batch (NSAMP+2048 -> mult 8)
#define XPTOT   (NBATCH * XPITCH)       // 3,560,832 elems
#define NCHUNK  (XPITCH / 8)            // 27819
#define CVTBLK  ((NBATCH * NCHUNK + 255) / 256)   // 1739
#define CHAINS_OFF ((size_t)(XPTOT + (size_t)TABCOLS * NFFT) * 2)  // 11,840,256
#define NEED_A     (CHAINS_OFF + NCHAINS * 3 * sizeof(int4))

// ---- fused prep: x->bf16 xp + LINEAR atom table + chain table --------------
__global__ void prep_all(const float* __restrict__ x,
                         __hip_bfloat16* __restrict__ xp,
                         __hip_bfloat16* __restrict__ tab,
                         int4* __restrict__ chains) {
    const int bid = blockIdx.x;
    if (bid < CVTBLK) {
        const int idx = bid * 256 + threadIdx.x;
        if (idx >= NBATCH * NCHUNK) return;
        const int b  = idx / NCHUNK;
        const int c  = idx - b * NCHUNK;
        const int i0 = c * 8;
        const float* xb = x + (size_t)b * NSAMP;
        const int g0 = i0 - PADW;
        union { short8 v; unsigned short u[8]; } pk;
        if (g0 >= 0 && g0 + 8 <= NSAMP) {
            const float4 f0 = *(const float4*)(xb + g0);
            const float4 f1 = *(const float4*)(xb + g0 + 4);
            const float vv[8] = {f0.x, f0.y, f0.z, f0.w, f1.x, f1.y, f1.z, f1.w};
            #pragma unroll
            for (int e = 0; e < 8; ++e) {
                __hip_bfloat16 h = __float2bfloat16(vv[e]);
                pk.u[e] = *(unsigned short*)&h;
            }
        } else {
            #pragma unroll
            for (int e = 0; e < 8; ++e) {
                const int g = g0 + e;
                const float v = (g >= 0 && g < NSAMP) ? xb[g] : 0.f;
                __hip_bfloat16 h = __float2bfloat16(v);
                pk.u[e] = *(unsigned short*)&h;
            }
        }
        *(short8*)(xp + (size_t)b * XPITCH + i0) = pk.v;
        return;
    }
    if (bid == CVTBLK + TABCOLS) {
        // ---- per-nt K-clip, then hardcoded chain composition ---------------
        __shared__ int s_k0[NT2], s_ns[NT2];
        const int nt = threadIdx.x;
        if (nt < NT2) {
            const int    bin0  = (nt * BN2) >> 1;
            const double freq  = 27.5 * exp2((double)bin0 / 60.0);
            const double r     = exp2(2.0 / 60.0);
            const double alpha = (r - 1.0) / (r + 1.0);
            const double len   = (1.0 / alpha) * (double)SRATE / (freq + 30.0 / alpha);
            const int    nk    = (int)floor(len);
            const int    s     = (NFFT - nk) / 2;
            const int    k0    = s & ~(BK2 - 1);
            int          k1    = (s + nk + BK2 - 1) & ~(BK2 - 1);
            if (k1 > NFFT) k1 = NFFT;
            s_k0[nt] = k0;
            s_ns[nt] = (k1 - k0) / BK2;
        }
        __syncthreads();
        if (threadIdx.x == 0) {
            // chains: {0},{1},{2},{3},{4},{5,8},{6,7}  (steps ~46,46,44,42,40,44,42)
            const int comp[NCHAINS][3] = {
                {0,-1,-1},{1,-1,-1},{2,-1,-1},{3,-1,-1},{4,-1,-1},{5,8,-1},{6,7,-1}};
            for (int c = 0; c < NCHAINS; ++c)
                for (int k = 0; k < 3; ++k) {
                    const int q = comp[c][k];
                    chains[c * 3 + k] = (q >= 0)
                        ? make_int4(q, s_k0[q], s_ns[q], 0)
                        : make_int4(0, 0, 0, 0);
                }
        }
        return;
    }
    // ---- atom table col (LINEAR layout [col][k]) ---------------------------
    const int col = bid - CVTBLK;                     // 0..1151
    const int bin = col >> 1;
    const int ri  = col & 1;
    __hip_bfloat16* row = tab + (size_t)col * NFFT;
    {
        const short8 z8 = {0,0,0,0,0,0,0,0};
        *(short8*)(row + threadIdx.x * 8) = z8;       // zero all 2048
    }
    if (bin >= NBINS) return;
    __syncthreads();
    const double freq  = 27.5 * exp2((double)bin / 60.0);
    const double r     = exp2(2.0 / 60.0);
    const double alpha = (r - 1.0) / (r + 1.0);
    const double len   = (1.0 / alpha) * (double)SRATE / (freq + 30.0 / alpha);
    const int    nk    = (int)floor(len);
    const int    s     = (NFFT - nk) / 2;
    const float  ampf  = (float)((2.0 / (double)(nk - 1)) / sqrt(len));
    const float  winc  = 2.0f / (float)(nk - 1);
    const float  phsf  = (float)(2.0 * freq / (double)SRATE);  // revolutions/tap
    for (int tp = threadIdx.x; tp < nk; tp += 256) {
        const float w = 0.5f - 0.5f * cospif(winc * (float)tp);
        const float ph = fmodf(phsf * (float)tp, 2.0f);
        float sp, cp;
        sincospif(ph, &sp, &cp);
        const float val = ri ? (-w * ampf * sp) : (w * ampf * cp);
        row[s + tp] = __float2bfloat16(val);
    }
}

// ---- GEMM: out[row*540+bin] = |sum_k xp_row[k] * atom_col[k]| --------------
__global__ __launch_bounds__(256, 3) void vqt_gemm10(const __hip_bfloat16* __restrict__ xp,
                                                     const __hip_bfloat16* __restrict__ tab,
                                                     const int4* __restrict__ chains,
                                                     float* __restrict__ out) {
    // 48 KB: 3 x [A 8K | B 8K]
    __shared__ uint4 smem4[3072];
    const int mt = blockIdx.x;
    const int4 seg0 = chains[blockIdx.y * 3 + 0];
    const int4 seg1 = chains[blockIdx.y * 3 + 1];
    const int4 seg2 = chains[blockIdx.y * 3 + 2];
    const int ns0 = seg0.z, ns1 = seg1.z, ns2 = seg2.z;
    const int total = ns0 + ns1 + ns2;
    const int row0 = mt * BM2;

    const int t    = threadIdx.x;
    const int lane = t & 63;
    const int w    = t >> 6;
    const int wr   = w >> 1, wc = w & 1;              // wave -> 64x64 quadrant
    const int l15  = lane & 15, kq = lane >> 4;

    // thread-constant staging geometry (r8-proven conflict-free slot map)
    size_t aoff[2]; int lrB[2], kq8[2];
    #pragma unroll
    for (int p = 0; p < 2; ++p) {
        const int c   = t + 256 * p;                  // 0..511
        const int lr  = c >> 2;                       // row 0..127
        const int chp = c & 3;                        // phys chunk
        const int kqs = (chp - (lr >> 1)) & 3;        // k-chunk held by slot
        int row = row0 + lr;
        if (row > MROWS - 1) row = MROWS - 1;
        const int bb = row / NFRAMES;
        const int ff = row - bb * NFRAMES;
        aoff[p] = (size_t)bb * XPITCH + (size_t)ff * HOPSZ + (kqs << 3);
        lrB[p] = lr; kq8[p] = kqs << 3;
    }

    // stage-side cursor over the chain's concatenated step stream
    const __hip_bfloat16* sA[2];
    const __hip_bfloat16* sB[2];
    int sseg = 0, soff = 0, scur_ns = ns0;
    #pragma unroll
    for (int p = 0; p < 2; ++p) {
        sA[p] = xp + aoff[p] + seg0.y;
        sB[p] = tab + (size_t)(seg0.x * BN2 + lrB[p]) * NFFT + kq8[p] + seg0.y;
    }
    auto advance_stage = [&]() {
        ++soff;
        if (soff == scur_ns) {
            soff = 0; ++sseg;
            const int4 sg = (sseg == 1) ? seg1 : seg2;
            if (sseg < 3 && sg.z > 0) {
                scur_ns = sg.z;
                #pragma unroll
                for (int p = 0; p < 2; ++p) {
                    sA[p] = xp + aoff[p] + sg.y;
                    sB[p] = tab + (size_t)(sg.x * BN2 + lrB[p]) * NFFT + kq8[p] + sg.y;
                }
            }
        } else {
            #pragma unroll
            for (int p = 0; p < 2; ++p) { sA[p] += BK2; sB[p] += BK2; }
        }
    };

    f32x4 acc[4][4] = {};

    // one STAGE = 4 gload_lds per thread (2 A + 2 B)
    #define STAGE(BUF)                                                            \
        do {                                                                      \
            const int cb = (BUF) * 1024;                                          \
            _Pragma("unroll")                                                     \
            for (int p = 0; p < 2; ++p)                                           \
                __builtin_amdgcn_global_load_lds((const void*)sA[p],              \
                    (void*)&smem4[cb + p * 256 + w * 64], 16, 0, 0);              \
            _Pragma("unroll")                                                     \
            for (int p = 0; p < 2; ++p)                                           \
                __builtin_amdgcn_global_load_lds((const void*)sB[p],              \
                    (void*)&smem4[cb + 512 + p * 256 + w * 64], 16, 0, 0);        \
            advance_stage();                                                      \
        } while (0)

    STAGE(0);
    STAGE(1);

    // per-lane phys chunk for reads (r8-proven)
    const int chrd = ((l15 >> 1) + kq) & 3;
    const int abase = (wr * 64 + l15) * 64 + chrd * 16;   // + i*1024
    const int bbase = (wc * 64 + l15) * 64 + chrd * 16;   // + j*1024

    // epilogue (r3-proven verbatim, parameterized by nt)
    auto epilogue = [&](int nt_c) {
        const int n0   = nt_c * BN2;
        const int rowb = row0 + wr * 64;
        const int binb = (n0 + wc * 64) >> 1;
        const int srcl = (lane & 48) | ((l15 & 7) << 1);
        #pragma unroll
        for (int i = 0; i < 4; ++i) {
            #pragma unroll
            for (int jp = 0; jp < 2; ++jp) {
                #pragma unroll
                for (int reg = 0; reg < 4; ++reg) {
                    const float v0 = acc[i][2 * jp][reg];
                    const float v1 = acc[i][2 * jp + 1][reg];
                    const float p0 = __shfl_xor(v0, 1);
                    const float p1 = __shfl_xor(v1, 1);
                    const float m0 = sqrtf(v0 * v0 + p0 * p0);
                    const float m1 = sqrtf(v1 * v1 + p1 * p1);
                    const float r0 = __shfl(m0, srcl);
                    const float r1 = __shfl(m1, srcl);
                    const float m  = (l15 < 8) ? r0 : r1;
                    const int row = rowb + i * 16 + kq * 4 + reg;
                    const int bin = binb + jp * 16 + l15;
                    if (row < MROWS && bin < NBINS)
                        out[(size_t)row * NBINS + bin] = m;
                }
            }
        }
    };

    int cseg = 0, coff = 0, cur = 0, stg = 2;
    for (int s = 0; s < total; ++s) {
        // r5/r8-PROVEN ordering: own-vmcnt -> barrier -> STAGE -> compute.
        // (epilogue stores share vmcnt; vmcnt(4) conservatively waits them too)
        if (s + 1 < total) {
            asm volatile("s_waitcnt vmcnt(4)" ::: "memory");
        } else {
            asm volatile("s_waitcnt vmcnt(0)" ::: "memory");
        }
        __builtin_amdgcn_sched_barrier(0);
        __builtin_amdgcn_s_barrier();
        __builtin_amdgcn_sched_barrier(0);
        if (s + 2 < total) {
            STAGE(stg);                               // WAR-safe: readers of stg
            stg = (stg == 2) ? 0 : stg + 1;           // passed this barrier
        }
        const char* Ab = (const char*)smem4 + cur * 16384;
        const char* Bb = Ab + 8192;
        short8 af[4], bf[4];
        #pragma unroll
        for (int i = 0; i < 4; ++i) af[i] = *(const short8*)(Ab + abase + i * 1024);
        #pragma unroll
        for (int j = 0; j < 4; ++j) bf[j] = *(const short8*)(Bb + bbase + j * 1024);
        #pragma unroll
        for (int i = 0; i < 4; ++i)
            #pragma unroll
            for (int j = 0; j < 4; ++j)
                acc[i][j] = __builtin_amdgcn_mfma_f32_16x16x32_bf16(af[i], bf[j], acc[i][j], 0, 0, 0);
        cur = (cur == 2) ? 0 : cur + 1;

        ++coff;
        const int ns_c = (cseg == 0) ? ns0 : (cseg == 1 ? ns1 : ns2);
        if (coff == ns_c) {
            const int nt_c = (cseg == 0) ? seg0.x : (cseg == 1 ? seg1.x : seg2.x);
            epilogue(nt_c);
            #pragma unroll
            for (int i = 0; i < 4; ++i)
                #pragma unroll
                for (int j = 0; j < 4; ++j)
                    acc[i][j] = f32x4{0.f, 0.f, 0.f, 0.f};
            ++cseg; coff = 0;
        }
    }
    #undef STAGE
}

// ======================= PATH B fallback: round-2 kernel ====================
#define NPADB   544
#define NCOLS   1088
#define BM 64
#define BN 64
#define BK 64
#define MTILES 7
#define NTILES 17
#define APITCH 72

__global__ void build_tab(__hip_bfloat16* __restrict__ tab) {
    const int bin = blockIdx.x;
    __hip_bfloat16* rowre = tab + (size_t)(2 * bin) * NFFT;
    __hip_bfloat16* rowim = rowre + NFFT;
    if (bin >= NBINS) {
        const __hip_bfloat16 z = __float2bfloat16(0.f);
        for (int t = threadIdx.x; t < NFFT; t += blockDim.x) { rowre[t] = z; rowim[t] = z; }
        return;
    }
    const double freq  = 27.5 * exp2((double)bin / 60.0);
    const double r     = exp2(2.0 / 60.0);
    const double alpha = (r - 1.0) / (r + 1.0);
    const double len   = (1.0 / alpha) * (double)SRATE / (freq + 30.0 / alpha);
    const int    nk    = (int)floor(len);
    const int    s     = (NFFT - nk) / 2;
    const double amp   = (2.0 / (double)(nk - 1)) / sqrt(len);
    for (int t = threadIdx.x; t < NFFT; t += blockDim.x) {
        float re = 0.f, im = 0.f;
        const int tp = t - s;
        if (tp >= 0 && tp < nk) {
            const double w  = 0.5 - 0.5 * cos(2.0 * PI_D * (double)tp / (double)(nk - 1));
            const double ph = fmod(2.0 * freq * (double)tp / (double)SRATE, 2.0);
            double sp, cp;
            sincospi(ph, &sp, &cp);
            re = (float)(w * amp * cp);
            im = (float)(-w * amp * sp);
        }
        rowre[t] = __float2bfloat16(re);
        rowim[t] = __float2bfloat16(im);
    }
}

__global__ __launch_bounds__(256) void vqt_gemm(const float* __restrict__ x,
                                                const __hip_bfloat16* __restrict__ tab,
                                                float* __restrict__ out) {
    __shared__ __hip_bfloat16 As[BM * APITCH];
    __shared__ __hip_bfloat16 Bs[BN * APITCH];
    const int mt = blockIdx.x, nt = blockIdx.y, b = blockIdx.z;
    const int n0 = nt * BN;
    const int    bin0  = n0 >> 1;
    const double freq  = 27.5 * exp2((double)bin0 / 60.0);
    const double r     = exp2(2.0 / 60.0);
    const double alpha = (r - 1.0) / (r + 1.0);
    const double len   = (1.0 / alpha) * (double)SRATE / (freq + 30.0 / alpha);
    const int    nk    = (int)floor(len);
    const int    s     = (NFFT - nk) / 2;
    const int    k0    = s & ~(BK - 1);
    int          k1    = (s + nk + BK - 1) & ~(BK - 1);
    if (k1 > NFFT) k1 = NFFT;
    const int tid  = threadIdx.x;
    const int lane = tid & 63;
    const int wid  = tid >> 6;
    const int wr   = wid >> 1, wc = wid & 1;
    const int sr   = tid >> 2, sq = tid & 3;
    const float* xb     = x + (size_t)b * NSAMP;
    const int    f_base = mt * BM;
    const long arow_off = (long)(f_base + sr) * HOPSZ - PADW + sq * 16;
    const __hip_bfloat16* brow = tab + (size_t)(n0 + sr) * NFFT + sq * 16;
    f32x4 acc[2][2] = {};
    for (int kt = k0; kt < k1; kt += BK) {
        union { short8 v[2]; unsigned short u[16]; } pk;
        #pragma unroll
        for (int v = 0; v < 4; ++v) {
            const long g = arow_off + kt + v * 4;
            float4 t4 = {0.f, 0.f, 0.f, 0.f};
            if (g >= 0 && g + 4 <= (long)NSAMP) t4 = *(const float4*)(xb + g);
            __hip_bfloat16 h0 = __float2bfloat16(t4.x);
            __hip_bfloat16 h1 = __float2bfloat16(t4.y);
            __hip_bfloat16 h2 = __float2bfloat16(t4.z);
            __hip_bfloat16 h3 = __float2bfloat16(t4.w);
            pk.u[4 * v + 0] = *(unsigned short*)&h0;
            pk.u[4 * v + 1] = *(unsigned short*)&h1;
            pk.u[4 * v + 2] = *(unsigned short*)&h2;
            pk.u[4 * v + 3] = *(unsigned short*)&h3;
        }
        { short8* dst = (short8*)(As + sr * APITCH + sq * 16); dst[0] = pk.v[0]; dst[1] = pk.v[1]; }
        { const short8* src = (const short8*)(brow + kt);
          short8* dst = (short8*)(Bs + sr * APITCH + sq * 16); dst[0] = src[0]; dst[1] = src[1]; }
        __syncthreads();
        #pragma unroll
        for (int ks = 0; ks < 2; ++ks) {
            const int kc = ks * 32 + (lane >> 4) * 8;
            const short8 a0 = *(const short8*)(As + (wr * 32 +      (lane & 15)) * APITCH + kc);
            const short8 a1 = *(const short8*)(As + (wr * 32 + 16 + (lane & 15)) * APITCH + kc);
            const short8 b0 = *(const short8*)(Bs + (wc * 32 +      (lane & 15)) * APITCH + kc);
            const short8 b1 = *(const short8*)(Bs + (wc * 32 + 16 + (lane & 15)) * APITCH + kc);
            acc[0][0] = __builtin_amdgcn_mfma_f32_16x16x32_bf16(a0, b0, acc[0][0], 0, 0, 0);
            acc[0][1] = __builtin_amdgcn_mfma_f32_16x16x32_bf16(a0, b1, acc[0][1], 0, 0, 0);
            acc[1][0] = __builtin_amdgcn_mfma_f32_16x16x32_bf16(a1, b0, acc[1][0], 0, 0, 0);
            acc[1][1] = __builtin_amdgcn_mfma_f32_16x16x32_bf16(a1, b1, acc[1][1], 0, 0, 0);
        }
        __syncthreads();
    }
    const int colc = lane & 15, rg = lane >> 4;
    float* outb = out + (size_t)b * NFRAMES * NBINS;
    #pragma unroll
    for (int i = 0; i < 2; ++i)
        #pragma unroll
        for (int j = 0; j < 2; ++j)
            #pragma unroll
            for (int reg = 0; reg < 4; ++reg) {
                const float v = acc[i][j][reg];
                const float p = __shfl_xor(v, 1);
                if (!(lane & 1)) {
                    const int f   = f_base + wr * 32 + i * 16 + rg * 4 + reg;
                    const int col = n0 + wc * 32 + j * 16 + colc;
                    const int bin = col >> 1;
                    if (f < NFRAMES && bin < NBINS)
                        outb[(size_t)f * NBINS + bin] = sqrtf(v * v + p * p);
                }
            }
}

extern "C" void kernel_launch(void* const* d_in, const int* in_sizes, int n_in,
                              void* d_out, int out_size, void* d_ws, size_t ws_size,
                              hipStream_t stream) {
    const float* x = (const float*)d_in[0];
    float* out = (float*)d_out;
    const size_t needB = (size_t)NCOLS * NFFT * sizeof(__hip_bfloat16); // 4.46 MB
    if (ws_size >= NEED_A) {
        __hip_bfloat16* xp   = (__hip_bfloat16*)d_ws;
        __hip_bfloat16* tab  = xp + XPTOT;
        int4* chains = (int4*)((char*)d_ws + CHAINS_OFF);
        prep_all<<<dim3(CVTBLK + TABCOLS + 1), dim3(256), 0, stream>>>(x, xp, tab, chains);
        vqt_gemm10<<<dim3(MT2, NCHAINS), dim3(256), 0, stream>>>(xp, tab, chains, out);
    } else if (ws_size >= needB) {
        build_tab<<<dim3(NPADB), dim3(256), 0, stream>>>((__hip_bfloat16*)d_ws);
        vqt_gemm<<<dim3(MTILES, NTILES, NBATCH), dim3(256), 0, stream>>>(
            x, (const __hip_bfloat16*)d_ws, out);
    }
}

// Round 12
// 54.785 us; speedup vs baseline: 3.7783x; 1.1268x over previous
//
#include <hip/hip_runtime.h>
#include <hip/hip_bf16.h>
#include <math.h>

#define SRATE   44100
#define HOPSZ   512
#define NFFT    2048
#define PADW    1024
#define NBINS   540
#define NFRAMES 431
#define NSAMP   220500
#define NBATCH  16

#define PI_D 3.14159265358979323846

typedef __attribute__((ext_vector_type(8))) short short8;
typedef __attribute__((ext_vector_type(4))) float f32x4;

// ================== PATH A: phase-split pipelined GEMM (T3+T5) ==============
// M = batch*frames = 6896 rows, tile 128x128, BK=32, 4 waves 2x2 (64x64/wave).
// r8-PROVEN tile-level sync: vmcnt(4) -> barrier -> ... 3x16KB buffers.
// NEW (m201/m218 regime gate): each K-tile split into 2 phases
//   {ds_reads + gload issue -> barrier -> setprio(1) MFMA x8 setprio(0) -> barrier}
// Phase barriers are clustering-only (no data-ordering role): reads hit cur,
// stage writes hit stg=(cur+2)%3. Barrier density 1 per 8 K-elems (= m201).
#define MROWS   (NBATCH * NFRAMES)      // 6896
#define BM2     128
#define BN2     128
#define BK2     32
#define MT2     54                      // ceil(6896/128)
#define NT2     9
#define TABCOLS 1152                    // 9*128 cols (bins >=540 zero)
#define XPITCH  222552                  // bf16 elems per batch (NSAMP+2048 -> mult 8)
#define XPTOT   (NBATCH * XPITCH)       // 3,560,832 elems
#define NCHUNK  (XPITCH / 8)            // 27819
#define CVTBLK  ((NBATCH * NCHUNK + 255) / 256)   // 1739
#define KKOFF   (XPTOT + (size_t)TABCOLS * NFFT)  // bf16-elem offset of kktab
#define NEED_A  (KKOFF * 2 + NT2 * sizeof(int2))

// ---- fused prep: x->bf16 xp + LINEAR atom table + K-clip table -------------
__global__ void prep_all(const float* __restrict__ x,
                         __hip_bfloat16* __restrict__ xp,
                         __hip_bfloat16* __restrict__ tab,
                         int2* __restrict__ kktab) {
    const int bid = blockIdx.x;
    if (bid < CVTBLK) {
        const int idx = bid * 256 + threadIdx.x;
        if (idx >= NBATCH * NCHUNK) return;
        const int b  = idx / NCHUNK;
        const int c  = idx - b * NCHUNK;
        const int i0 = c * 8;
        const float* xb = x + (size_t)b * NSAMP;
        const int g0 = i0 - PADW;
        union { short8 v; unsigned short u[8]; } pk;
        if (g0 >= 0 && g0 + 8 <= NSAMP) {
            const float4 f0 = *(const float4*)(xb + g0);
            const float4 f1 = *(const float4*)(xb + g0 + 4);
            const float vv[8] = {f0.x, f0.y, f0.z, f0.w, f1.x, f1.y, f1.z, f1.w};
            #pragma unroll
            for (int e = 0; e < 8; ++e) {
                __hip_bfloat16 h = __float2bfloat16(vv[e]);
                pk.u[e] = *(unsigned short*)&h;
            }
        } else {
            #pragma unroll
            for (int e = 0; e < 8; ++e) {
                const int g = g0 + e;
                const float v = (g >= 0 && g < NSAMP) ? xb[g] : 0.f;
                __hip_bfloat16 h = __float2bfloat16(v);
                pk.u[e] = *(unsigned short*)&h;
            }
        }
        *(short8*)(xp + (size_t)b * XPITCH + i0) = pk.v;
        return;
    }
    if (bid == CVTBLK + TABCOLS) {
        const int nt = threadIdx.x;
        if (nt < NT2) {
            const int    bin0  = (nt * BN2) >> 1;
            const double freq  = 27.5 * exp2((double)bin0 / 60.0);
            const double r     = exp2(2.0 / 60.0);
            const double alpha = (r - 1.0) / (r + 1.0);
            const double len   = (1.0 / alpha) * (double)SRATE / (freq + 30.0 / alpha);
            const int    nk    = (int)floor(len);
            const int    s     = (NFFT - nk) / 2;
            const int    k0    = s & ~(BK2 - 1);
            int          k1    = (s + nk + BK2 - 1) & ~(BK2 - 1);
            if (k1 > NFFT) k1 = NFFT;
            kktab[nt] = make_int2(k0, (k1 - k0) / BK2);
        }
        return;
    }
    // ---- atom table col (LINEAR layout [col][k]) ---------------------------
    const int col = bid - CVTBLK;                     // 0..1151
    const int bin = col >> 1;
    const int ri  = col & 1;
    __hip_bfloat16* row = tab + (size_t)col * NFFT;
    {
        const short8 z8 = {0,0,0,0,0,0,0,0};
        *(short8*)(row + threadIdx.x * 8) = z8;       // zero all 2048
    }
    if (bin >= NBINS) return;
    __syncthreads();
    const double freq  = 27.5 * exp2((double)bin / 60.0);
    const double r     = exp2(2.0 / 60.0);
    const double alpha = (r - 1.0) / (r + 1.0);
    const double len   = (1.0 / alpha) * (double)SRATE / (freq + 30.0 / alpha);
    const int    nk    = (int)floor(len);
    const int    s     = (NFFT - nk) / 2;
    const float  ampf  = (float)((2.0 / (double)(nk - 1)) / sqrt(len));
    const float  winc  = 2.0f / (float)(nk - 1);
    const float  phsf  = (float)(2.0 * freq / (double)SRATE);  // revolutions/tap
    for (int tp = threadIdx.x; tp < nk; tp += 256) {
        const float w = 0.5f - 0.5f * cospif(winc * (float)tp);
        const float ph = fmodf(phsf * (float)tp, 2.0f);
        float sp, cp;
        sincospif(ph, &sp, &cp);
        const float val = ri ? (-w * ampf * sp) : (w * ampf * cp);
        row[s + tp] = __float2bfloat16(val);
    }
}

// ---- GEMM: out[row*540+bin] = |sum_k xp_row[k] * atom_col[k]| --------------
__global__ __launch_bounds__(256, 3) void vqt_gemm11(const __hip_bfloat16* __restrict__ xp,
                                                     const __hip_bfloat16* __restrict__ tab,
                                                     const int2* __restrict__ kktab,
                                                     float* __restrict__ out) {
    // 48 KB: 3 x [A 8K | B 8K]
    __shared__ uint4 smem4[3072];
    const int mt = blockIdx.x, nt = blockIdx.y;
    const int row0 = mt * BM2;
    const int n0   = nt * BN2;

    const int2 kkv    = kktab[nt];
    const int  k0     = kkv.x;
    const int  nsteps = kkv.y;                        // 10..46

    const int t    = threadIdx.x;
    const int lane = t & 63;
    const int w    = t >> 6;
    const int wr   = w >> 1, wc = w & 1;              // wave -> 64x64 quadrant
    const int l15  = lane & 15, kq = lane >> 4;

    // staging sources (r8-proven conflict-free slot map): 2 A + 2 B per thread
    const __hip_bfloat16* srcA[2];
    const __hip_bfloat16* srcB[2];
    #pragma unroll
    for (int p = 0; p < 2; ++p) {
        const int c   = t + 256 * p;                  // 0..511
        const int lr  = c >> 2;                       // row 0..127
        const int chp = c & 3;                        // phys chunk
        const int kqs = (chp - (lr >> 1)) & 3;        // k-chunk held by slot
        int row = row0 + lr;
        if (row > MROWS - 1) row = MROWS - 1;
        const int bb = row / NFRAMES;
        const int ff = row - bb * NFRAMES;
        srcA[p] = xp + (size_t)bb * XPITCH + (size_t)ff * HOPSZ + (kqs << 3) + k0;
        srcB[p] = tab + (size_t)(n0 + lr) * NFFT + (kqs << 3) + k0;
    }

    f32x4 acc[4][4] = {};

    #define STAGE_A(BUF)                                                          \
        do {                                                                      \
            const int cb = (BUF) * 1024;                                          \
            _Pragma("unroll")                                                     \
            for (int p = 0; p < 2; ++p) {                                         \
                __builtin_amdgcn_global_load_lds((const void*)srcA[p],            \
                    (void*)&smem4[cb + p * 256 + w * 64], 16, 0, 0);              \
                srcA[p] += BK2;                                                   \
            }                                                                     \
        } while (0)
    #define STAGE_B(BUF)                                                          \
        do {                                                                      \
            const int cb = (BUF) * 1024;                                          \
            _Pragma("unroll")                                                     \
            for (int p = 0; p < 2; ++p) {                                         \
                __builtin_amdgcn_global_load_lds((const void*)srcB[p],            \
                    (void*)&smem4[cb + 512 + p * 256 + w * 64], 16, 0, 0);        \
                srcB[p] += BK2;                                                   \
            }                                                                     \
        } while (0)

    STAGE_A(0); STAGE_B(0);
    STAGE_A(1); STAGE_B(1);

    // per-lane phys chunk for reads (r8-proven)
    const int chrd = ((l15 >> 1) + kq) & 3;
    const int abase = (wr * 64 + l15) * 64 + chrd * 16;   // + i*1024
    const int bbase = (wc * 64 + l15) * 64 + chrd * 16;   // + j*1024

    int cur = 0, stg = 2;
    for (int step = 0; step < nsteps; ++step) {
        // r8-PROVEN tile-level ordering: own-vmcnt -> barrier.
        if (step + 1 < nsteps) {
            asm volatile("s_waitcnt vmcnt(4)" ::: "memory");
        } else {
            asm volatile("s_waitcnt vmcnt(0)" ::: "memory");
        }
        __builtin_amdgcn_sched_barrier(0);
        __builtin_amdgcn_s_barrier();
        __builtin_amdgcn_sched_barrier(0);
        const bool willstage = (step + 2 < nsteps);
        const char* Ab = (const char*)smem4 + cur * 16384;
        const char* Bb = Ab + 8192;

        // ---- phase 0: af0,af1 + bf0..3 reads; issue A-half of next stage ----
        short8 af0 = *(const short8*)(Ab + abase);
        short8 af1 = *(const short8*)(Ab + abase + 1024);
        short8 bf[4];
        #pragma unroll
        for (int j = 0; j < 4; ++j) bf[j] = *(const short8*)(Bb + bbase + j * 1024);
        if (willstage) STAGE_A(stg);
        __builtin_amdgcn_s_barrier();                 // clustering only
        __builtin_amdgcn_s_setprio(1);
        #pragma unroll
        for (int j = 0; j < 4; ++j) {
            acc[0][j] = __builtin_amdgcn_mfma_f32_16x16x32_bf16(af0, bf[j], acc[0][j], 0, 0, 0);
            acc[1][j] = __builtin_amdgcn_mfma_f32_16x16x32_bf16(af1, bf[j], acc[1][j], 0, 0, 0);
        }
        __builtin_amdgcn_s_setprio(0);
        __builtin_amdgcn_s_barrier();                 // clustering only

        // ---- phase 1: af2,af3 reads; issue B-half of next stage -------------
        short8 af2 = *(const short8*)(Ab + abase + 2048);
        short8 af3 = *(const short8*)(Ab + abase + 3072);
        if (willstage) STAGE_B(stg);
        __builtin_amdgcn_s_barrier();                 // clustering only
        __builtin_amdgcn_s_setprio(1);
        #pragma unroll
        for (int j = 0; j < 4; ++j) {
            acc[2][j] = __builtin_amdgcn_mfma_f32_16x16x32_bf16(af2, bf[j], acc[2][j], 0, 0, 0);
            acc[3][j] = __builtin_amdgcn_mfma_f32_16x16x32_bf16(af3, bf[j], acc[3][j], 0, 0, 0);
        }
        __builtin_amdgcn_s_setprio(0);

        if (willstage) stg = (stg == 2) ? 0 : stg + 1;
        cur = (cur == 2) ? 0 : cur + 1;
    }
    #undef STAGE_A
    #undef STAGE_B

    // ---- epilogue: |(re,im)| of adjacent-lane pairs (r3-proven verbatim)
    const int rowb = row0 + wr * 64;
    const int binb = (n0 + wc * 64) >> 1;
    const int srcl = (lane & 48) | ((l15 & 7) << 1);
    #pragma unroll
    for (int i = 0; i < 4; ++i) {
        #pragma unroll
        for (int jp = 0; jp < 2; ++jp) {
            #pragma unroll
            for (int reg = 0; reg < 4; ++reg) {
                const float v0 = acc[i][2 * jp][reg];
                const float v1 = acc[i][2 * jp + 1][reg];
                const float p0 = __shfl_xor(v0, 1);
                const float p1 = __shfl_xor(v1, 1);
                const float m0 = sqrtf(v0 * v0 + p0 * p0);
                const float m1 = sqrtf(v1 * v1 + p1 * p1);
                const float r0 = __shfl(m0, srcl);
                const float r1 = __shfl(m1, srcl);
                const float m  = (l15 < 8) ? r0 : r1;
                const int row = rowb + i * 16 + kq * 4 + reg;
                const int bin = binb + jp * 16 + l15;
                if (row < MROWS && bin < NBINS)
                    out[(size_t)row * NBINS + bin] = m;
            }
        }
    }
}

// ======================= PATH B fallback: round-2 kernel ====================
#define NPADB   544
#define NCOLS   1088
#define BM 64
#define BN 64
#define BK 64
#define MTILES 7
#define NTILES 17
#define APITCH 72

__global__ void build_tab(__hip_bfloat16* __restrict__ tab) {
    const int bin = blockIdx.x;
    __hip_bfloat16* rowre = tab + (size_t)(2 * bin) * NFFT;
    __hip_bfloat16* rowim = rowre + NFFT;
    if (bin >= NBINS) {
        const __hip_bfloat16 z = __float2bfloat16(0.f);
        for (int t = threadIdx.x; t < NFFT; t += blockDim.x) { rowre[t] = z; rowim[t] = z; }
        return;
    }
    const double freq  = 27.5 * exp2((double)bin / 60.0);
    const double r     = exp2(2.0 / 60.0);
    const double alpha = (r - 1.0) / (r + 1.0);
    const double len   = (1.0 / alpha) * (double)SRATE / (freq + 30.0 / alpha);
    const int    nk    = (int)floor(len);
    const int    s     = (NFFT - nk) / 2;
    const double amp   = (2.0 / (double)(nk - 1)) / sqrt(len);
    for (int t = threadIdx.x; t < NFFT; t += blockDim.x) {
        float re = 0.f, im = 0.f;
        const int tp = t - s;
        if (tp >= 0 && tp < nk) {
            const double w  = 0.5 - 0.5 * cos(2.0 * PI_D * (double)tp / (double)(nk - 1));
            const double ph = fmod(2.0 * freq * (double)tp / (double)SRATE, 2.0);
            double sp, cp;
            sincospi(ph, &sp, &cp);
            re = (float)(w * amp * cp);
            im = (float)(-w * amp * sp);
        }
        rowre[t] = __float2bfloat16(re);
        rowim[t] = __float2bfloat16(im);
    }
}

__global__ __launch_bounds__(256) void vqt_gemm(const float* __restrict__ x,
                                                const __hip_bfloat16* __restrict__ tab,
                                                float* __restrict__ out) {
    __shared__ __hip_bfloat16 As[BM * APITCH];
    __shared__ __hip_bfloat16 Bs[BN * APITCH];
    const int mt = blockIdx.x, nt = blockIdx.y, b = blockIdx.z;
    const int n0 = nt * BN;
    const int    bin0  = n0 >> 1;
    const double freq  = 27.5 * exp2((double)bin0 / 60.0);
    const double r     = exp2(2.0 / 60.0);
    const double alpha = (r - 1.0) / (r + 1.0);
    const double len   = (1.0 / alpha) * (double)SRATE / (freq + 30.0 / alpha);
    const int    nk    = (int)floor(len);
    const int    s     = (NFFT - nk) / 2;
    const int    k0    = s & ~(BK - 1);
    int          k1    = (s + nk + BK - 1) & ~(BK - 1);
    if (k1 > NFFT) k1 = NFFT;
    const int tid  = threadIdx.x;
    const int lane = tid & 63;
    const int wid  = tid >> 6;
    const int wr   = wid >> 1, wc = wid & 1;
    const int sr   = tid >> 2, sq = tid & 3;
    const float* xb     = x + (size_t)b * NSAMP;
    const int    f_base = mt * BM;
    const long arow_off = (long)(f_base + sr) * HOPSZ - PADW + sq * 16;
    const __hip_bfloat16* brow = tab + (size_t)(n0 + sr) * NFFT + sq * 16;
    f32x4 acc[2][2] = {};
    for (int kt = k0; kt < k1; kt += BK) {
        union { short8 v[2]; unsigned short u[16]; } pk;
        #pragma unroll
        for (int v = 0; v < 4; ++v) {
            const long g = arow_off + kt + v * 4;
            float4 t4 = {0.f, 0.f, 0.f, 0.f};
            if (g >= 0 && g + 4 <= (long)NSAMP) t4 = *(const float4*)(xb + g);
            __hip_bfloat16 h0 = __float2bfloat16(t4.x);
            __hip_bfloat16 h1 = __float2bfloat16(t4.y);
            __hip_bfloat16 h2 = __float2bfloat16(t4.z);
            __hip_bfloat16 h3 = __float2bfloat16(t4.w);
            pk.u[4 * v + 0] = *(unsigned short*)&h0;
            pk.u[4 * v + 1] = *(unsigned short*)&h1;
            pk.u[4 * v + 2] = *(unsigned short*)&h2;
            pk.u[4 * v + 3] = *(unsigned short*)&h3;
        }
        { short8* dst = (short8*)(As + sr * APITCH + sq * 16); dst[0] = pk.v[0]; dst[1] = pk.v[1]; }
        { const short8* src = (const short8*)(brow + kt);
          short8* dst = (short8*)(Bs + sr * APITCH + sq * 16); dst[0] = src[0]; dst[1] = src[1]; }
        __syncthreads();
        #pragma unroll
        for (int ks = 0; ks < 2; ++ks) {
            const int kc = ks * 32 + (lane >> 4) * 8;
            const short8 a0 = *(const short8*)(As + (wr * 32 +      (lane & 15)) * APITCH + kc);
            const short8 a1 = *(const short8*)(As + (wr * 32 + 16 + (lane & 15)) * APITCH + kc);
            const short8 b0 = *(const short8*)(Bs + (wc * 32 +      (lane & 15)) * APITCH + kc);
            const short8 b1 = *(const short8*)(Bs + (wc * 32 + 16 + (lane & 15)) * APITCH + kc);
            acc[0][0] = __builtin_amdgcn_mfma_f32_16x16x32_bf16(a0, b0, acc[0][0], 0, 0, 0);
            acc[0][1] = __builtin_amdgcn_mfma_f32_16x16x32_bf16(a0, b1, acc[0][1], 0, 0, 0);
            acc[1][0] = __builtin_amdgcn_mfma_f32_16x16x32_bf16(a1, b0, acc[1][0], 0, 0, 0);
            acc[1][1] = __builtin_amdgcn_mfma_f32_16x16x32_bf16(a1, b1, acc[1][1], 0, 0, 0);
        }
        __syncthreads();
    }
    const int colc = lane & 15, rg = lane >> 4;
    float* outb = out + (size_t)b * NFRAMES * NBINS;
    #pragma unroll
    for (int i = 0; i < 2; ++i)
        #pragma unroll
        for (int j = 0; j < 2; ++j)
            #pragma unroll
            for (int reg = 0; reg < 4; ++reg) {
                const float v = acc[i][j][reg];
                const float p = __shfl_xor(v, 1);
                if (!(lane & 1)) {
                    const int f   = f_base + wr * 32 + i * 16 + rg * 4 + reg;
                    const int col = n0 + wc * 32 + j * 16 + colc;
                    const int bin = col >> 1;
                    if (f < NFRAMES && bin < NBINS)
                        outb[(size_t)f * NBINS + bin] = sqrtf(v * v + p * p);
                }
            }
}

extern "C" void kernel_launch(void* const* d_in, const int* in_sizes, int n_in,
                              void* d_out, int out_size, void* d_ws, size_t ws_size,
                              hipStream_t stream) {
    const float* x = (const float*)d_in[0];
    float* out = (float*)d_out;
    const size_t needB = (size_t)NCOLS * NFFT * sizeof(__hip_bfloat16); // 4.46 MB
    if (ws_size >= NEED_A) {
        __hip_bfloat16* xp   = (__hip_bfloat16*)d_ws;
        __hip_bfloat16* tab  = xp + XPTOT;
        int2* kktab = (int2*)((char*)d_ws + KKOFF * 2);
        prep_all<<<dim3(CVTBLK + TABCOLS + 1), dim3(256), 0, stream>>>(x, xp, tab, kktab);
        vqt_gemm11<<<dim3(MT2, NT2), dim3(256), 0, stream>>>(xp, tab, kktab, out);
    } else if (ws_size >= needB) {
        build_tab<<<dim3(NPADB), dim3(256), 0, stream>>>((__hip_bfloat16*)d_ws);
        vqt_gemm<<<dim3(MTILES, NTILES, NBATCH), dim3(256), 0, stream>>>(
            x, (const __hip_bfloat16*)d_ws, out);
    }
}